// Round 9
// baseline (172.541 us; speedup 1.0000x reference)
//
#include <hip/hip_runtime.h>
#include <math.h>

#define NN 100
#define K 4                 // anchors per thread in match kernel
#define MBLK 64             // match block = 1 wave
#define ABLK (K * MBLK)     // 256 anchors per match block
#define FBLK 256            // finalize block

__device__ __forceinline__ float fast_rcp(float x) { return __builtin_amdgcn_rcpf(x); }

// ---------------------------------------------------------------------------
// DPP conditional-select step for the column (per-box) argmax reduction.
// Compare is the exact cross-multiply ratio test (other > mine  <=>
// oi*cs - ci*os > 0). bound_ctrl=1 injects (0,0,0) for invalid source lanes:
// fmaf(0, cs, -(ci*0)) == 0, never > 0 -> injected zeros can never win.
// DPP executes on the VALU at full rate (no LDS pipe -- a shfl-based
// butterfly would be LDS-bound at ~18 DS ops/(wave*box) and erase the gain).
// ---------------------------------------------------------------------------
template <int CTRL>
__device__ __forceinline__ void dpp_sel(float& ci, float& cs, int& cx) {
    float oi = __int_as_float(__builtin_amdgcn_update_dpp(
        0, __float_as_int(ci), CTRL, 0xF, 0xF, true));
    float os = __int_as_float(__builtin_amdgcn_update_dpp(
        0, __float_as_int(cs), CTRL, 0xF, 0xF, true));
    int ox = __builtin_amdgcn_update_dpp(0, cx, CTRL, 0xF, 0xF, true);
    if (fmaf(oi, cs, -(ci * os)) > 0.0f) { ci = oi; cs = os; cx = ox; }
}

// ---------------------------------------------------------------------------
// MERGED match kernel: ONE pass over all B*A*N pairs computes BOTH the
// per-anchor row argmax (pass A) and the per-box column argmax (old pass B).
// Block = 1 wave (64 threads) x K=4 anchors = 256 anchors of one image.
// - Boxes staged in LDS once (kills R1's per-iter global-load bloat).
// - Row state: serial loop n=0..99 in ORIGINAL box order, init (-1,1,0)
//   -> n=0 always updates -> zero rows keep idx 0 (R0/R1-verified exact
//   reference tie semantics via single-rounding fma cross-multiply).
// - Column: per-lane best over its K anchors (exact cross-multiply, lower k
//   = lower anchor wins ties), then 6-step DPP prefix-max (row_shr 1/2/4/8,
//   row_bcast15, row_bcast31) -> lane 63 holds the block winner; packed as
//   (iou_bits<<32)|(~anchor) u64 and atomicMax'd into packed[b][n].
//   Two-level scheme (exact local compare, rcp-packed u64 global max) is
//   byte-identical in risk class to the R1-verified SPLIT pipeline.
// ---------------------------------------------------------------------------
__global__ void __launch_bounds__(MBLK, 4) bbp_match(
    const float* __restrict__ anchors, const float* __restrict__ bboxes,
    float2* __restrict__ pa,                      // [B*A] (row max iou, idx)
    unsigned long long* __restrict__ packed,      // [B*NN] column winners
    int A, int NA) {
    const int tid = threadIdx.x;
    const int b = blockIdx.x / NA;
    const int base = (blockIdx.x - b * NA) * ABLK;

    __shared__ float4 sbox[NN];
    __shared__ float sarea[NN];
    for (int j = tid; j < NN; j += MBLK) {
        float4 v = *(const float4*)(bboxes + ((size_t)b * NN + j) * 4);
        sbox[j] = v;
        sarea[j] = (v.z - v.x) * (v.w - v.y);
    }
    __syncthreads();

    float ax1[K], ay1[K], ax2[K], ay2[K], aa[K];
    #pragma unroll
    for (int k = 0; k < K; ++k) {
        float4 ac = *(const float4*)(anchors + (size_t)(base + k * MBLK + tid) * 4);
        ax1[k] = fmaf(ac.z, -0.5f, ac.x);
        ay1[k] = fmaf(ac.w, -0.5f, ac.y);
        ax2[k] = fmaf(ac.z, 0.5f, ac.x);
        ay2[k] = fmaf(ac.w, 0.5f, ac.y);
        aa[k] = ac.z * ac.w;
    }
    float rin[K], rs[K];
    int ri[K];
    #pragma unroll
    for (int k = 0; k < K; ++k) { rin[k] = -1.0f; rs[k] = 1.0f; ri[k] = 0; }

    unsigned long long* pk = packed + (size_t)b * NN;

    #pragma unroll 2
    for (int n = 0; n < NN; ++n) {
        const float4 bv = sbox[n];           // LDS broadcast (1 ds_read_b128)
        const float sa = sarea[n];
        float ci = 0.0f, cs = 1.0f;
        int cx = 0;
        #pragma unroll
        for (int k = 0; k < K; ++k) {
            float w0 = fminf(ax2[k], bv.z) - fmaxf(ax1[k], bv.x);
            float h0 = fminf(ay2[k], bv.w) - fmaxf(ay1[k], bv.y);
            float inter = fmaxf(w0, 0.0f) * fmaxf(h0, 0.0f);
            float s = aa[k] + sa;
            // row argmax (strict >: first box wins ties, as reference)
            if (fmaf(inter, rs[k], -(rin[k] * s)) > 0.0f) {
                rin[k] = inter; rs[k] = s; ri[k] = n;
            }
            // column per-lane best (strict >: lower k = lower anchor wins)
            if (k == 0) { ci = inter; cs = s; cx = base + tid; }
            else if (fmaf(inter, cs, -(ci * s)) > 0.0f) {
                ci = inter; cs = s; cx = base + k * MBLK + tid;
            }
        }
        // 64-lane prefix-max on the VALU; result lands in lane 63
        dpp_sel<0x111>(ci, cs, cx);   // row_shr:1
        dpp_sel<0x112>(ci, cs, cx);   // row_shr:2
        dpp_sel<0x114>(ci, cs, cx);   // row_shr:4
        dpp_sel<0x118>(ci, cs, cx);   // row_shr:8
        dpp_sel<0x142>(ci, cs, cx);   // row_bcast15
        dpp_sel<0x143>(ci, cs, cx);   // row_bcast31
        if (tid == 63) {
            float iou = fmaxf(ci * fast_rcp(cs - ci), 0.0f);
            unsigned long long key =
                ((unsigned long long)__float_as_uint(iou) << 32)
                | (unsigned long long)(0xFFFFFFFFu - (unsigned)cx);
            atomicMax(&pk[n], key);   // fire-and-forget, 100 per block
        }
    }

    #pragma unroll
    for (int k = 0; k < K; ++k) {
        float2 r;
        r.x = rin[k] * fast_rcp(rs[k] - rin[k]);   // zero row -> 0
        r.y = __int_as_float(ri[k]);
        pa[(size_t)b * A + base + k * MBLK + tid] = r;   // coalesced
    }
}

// ---------------------------------------------------------------------------
// Finalize (R1/R7-verified body; only change: smax/override read directly
// from packed[b][n] instead of reducing SPLIT partials).
// ---------------------------------------------------------------------------
__global__ void __launch_bounds__(FBLK) bbp_finalize(
    const float* __restrict__ anchors, const float* __restrict__ bboxes,
    const int* __restrict__ labels, const float* __restrict__ mean4,
    const float* __restrict__ std4, const float* __restrict__ thr_p,
    const float2* __restrict__ pa,
    const unsigned long long* __restrict__ packed,
    float* __restrict__ out_conf, float* __restrict__ out_deltas,
    int A, int C) {
    const int b = blockIdx.y;
    const int tid = threadIdx.x;

    __shared__ float smax[NN];    // max_iou_of_bbox
    __shared__ float4 sbox[NN];   // gt boxes
    __shared__ int slab[NN];      // labels
    __shared__ int sovr[FBLK];    // override winner per local anchor (-1 none)
    sovr[tid] = -1;
    __syncthreads();
    if (tid < NN) {
        unsigned long long m = packed[(size_t)b * NN + tid];
        smax[tid] = __uint_as_float((unsigned)(m >> 32));
        unsigned an = 0xFFFFFFFFu - (unsigned)(m & 0xFFFFFFFFull);
        // segment_max over target ids: larger n wins -> atomicMax
        if ((an >> 8) == (unsigned)blockIdx.x)
            atomicMax(&sovr[an & (FBLK - 1)], tid);
        slab[tid] = labels[(size_t)b * NN + tid];
        sbox[tid] = *(const float4*)(bboxes + ((size_t)b * NN + tid) * 4);
    }
    __syncthreads();

    const int a = blockIdx.x * FBLK + tid;
    const size_t idx = (size_t)b * A + a;
    const float thr = thr_p[0];

    float2 pav = pa[idx];
    int ov = sovr[tid];
    bool valid = ov >= 0;
    int bi = valid ? ov : __float_as_int(pav.y);
    float mb = smax[bi];                      // max_iou_of_bbox[bi]
    float miou = valid ? mb : pav.x;
    float denom = fmaxf(mb, thr);
    if (miou < 0.5f * thr) miou = 0.0f;
    float score = miou * fast_rcp(denom);
    int lab = slab[bi];
    if (lab <= 0) { score = 0.0f; lab = 0; }

    for (int c = 0; c < C; ++c)
        out_conf[idx * (size_t)C + c] = (lab == c + 1) ? score : 0.0f;

    float4 bv = sbox[bi];
    float4 av = *(const float4*)(anchors + (size_t)a * 4);
    float cx = (bv.x + bv.z) * 0.5f;
    float cy = (bv.y + bv.w) * 0.5f;
    float bw = bv.z - bv.x;
    float bh = bv.w - bv.y;
    const float rz = fast_rcp(av.z), rw = fast_rcp(av.w);
    float4 d;
    d.x = ((cx - av.x) * rz - mean4[0]) * fast_rcp(std4[0]);
    d.y = ((cy - av.y) * rw - mean4[1]) * fast_rcp(std4[1]);
    d.z = (__logf(bw * rz) - mean4[2]) * fast_rcp(std4[2]);
    d.w = (__logf(bh * rw) - mean4[3]) * fast_rcp(std4[3]);
    *(float4*)(out_deltas + idx * 4) = d;
}

// ---------------------------------------------------------------------------
extern "C" void kernel_launch(void* const* d_in, const int* in_sizes, int n_in,
                              void* d_out, int out_size, void* d_ws, size_t ws_size,
                              hipStream_t stream) {
    const float* anchors = (const float*)d_in[0];
    const int* labels = (const int*)d_in[1];
    const float* bboxes = (const float*)d_in[2];
    const float* mean4 = (const float*)d_in[3];
    const float* std4 = (const float*)d_in[4];
    const float* thr_p = (const float*)d_in[5];

    const int A = in_sizes[0] / 4;        // 65536
    const int BN = in_sizes[1];           // 800
    const int B = BN / NN;                // 8
    const int C = out_size / (B * A) - 4; // 1
    const int NA = A / ABLK;              // 256 match blocks per image

    char* ws = (char*)d_ws;
    size_t off = 0;
    unsigned long long* packed = (unsigned long long*)ws;          // [B*NN]
    off += ((size_t)B * NN * sizeof(unsigned long long) + 255) & ~(size_t)255;
    float2* pa = (float2*)(ws + off);                              // [B*A]

    float* out_conf = (float*)d_out;
    float* out_deltas = out_conf + (size_t)B * A * C;

    // zero the column-winner accumulator (atomicMax from 0; all real keys > 0)
    hipMemsetAsync(packed, 0, (size_t)B * NN * sizeof(unsigned long long), stream);

    bbp_match<<<dim3(B * NA), dim3(MBLK), 0, stream>>>(
        anchors, bboxes, pa, packed, A, NA);

    bbp_finalize<<<dim3(A / FBLK, B), dim3(FBLK), 0, stream>>>(
        anchors, bboxes, labels, mean4, std4, thr_p, pa, packed,
        out_conf, out_deltas, A, C);
}